// Round 4
// baseline (448.013 us; speedup 1.0000x reference)
//
#include <hip/hip_runtime.h>
#include <hip/hip_bf16.h>

#define MROWS 8192   // N*T
#define KDIM  512    // CIN
#define NCOL  8192   // codebook size K
#define TSEQ  2048

typedef float f32x4 __attribute__((ext_vector_type(4)));
typedef __bf16 bf16x8 __attribute__((ext_vector_type(8)));

__device__ __forceinline__ unsigned short f2bf(float x) {
  unsigned int u = __float_as_uint(x);
  u += 0x7fffu + ((u >> 16) & 1u);
  return (unsigned short)(u >> 16);
}

// ---------------- conversions ----------------
__global__ void convA_kernel(const float* __restrict__ X, unsigned short* __restrict__ Y) {
  int i = blockIdx.x * 256 + threadIdx.x;
  float4 v = reinterpret_cast<const float4*>(X)[i];
  ushort4 o;
  o.x = f2bf(v.x); o.y = f2bf(v.y); o.z = f2bf(v.z); o.w = f2bf(v.w);
  reinterpret_cast<ushort4*>(Y)[i] = o;
}

__global__ void convB_kernel(const float* __restrict__ W, unsigned short* __restrict__ Bt) {
  __shared__ float tile[32][33];
  int bx = blockIdx.x, by = blockIdx.y;
  int tx = threadIdx.x, ty = threadIdx.y;
  #pragma unroll
  for (int i = 0; i < 32; i += 8)
    tile[ty + i][tx] = W[(size_t)(by * 32 + ty + i) * NCOL + bx * 32 + tx];
  __syncthreads();
  #pragma unroll
  for (int i = 0; i < 32; i += 8)
    Bt[(size_t)(bx * 32 + ty + i) * KDIM + by * 32 + tx] = f2bf(tile[tx][ty + i]);
}

// ---------------- f = normalize(feats @ proj), float4 feats loads ----------------
__global__ void fproj_kernel(const float* __restrict__ feats, const float* __restrict__ proj,
                             float* __restrict__ fnorm) {
  int tid = threadIdx.x;            // 256 = 16 rows x 16 dims
  int rl = tid >> 4, d = tid & 15;
  int row = blockIdx.x * 16 + rl;
  const float4* fr4 = reinterpret_cast<const float4*>(feats + (size_t)row * KDIM);
  float acc = 0.f;
  #pragma unroll 4
  for (int kc = 0; kc < KDIM / 4; ++kc) {
    float4 v = fr4[kc];
    const float* p = proj + (size_t)kc * 64 + d;   // proj[(4kc+i)*16 + d]
    acc += v.x * p[0] + v.y * p[16] + v.z * p[32] + v.w * p[48];
  }
  float s = acc * acc;
  #pragma unroll
  for (int o = 1; o < 16; o <<= 1) s += __shfl_xor(s, o);
  float nrm = sqrtf(s);
  fnorm[(size_t)row * 16 + d] = acc / fmaxf(nrm, 1e-12f);
}

// ---------------- nearest codebook (partials, cc fused) ----------------
#define CB_CODES 128
__global__ __launch_bounds__(256)
void targets_part_kernel(const float* __restrict__ fnorm, const float* __restrict__ cb,
                         float* __restrict__ pval, int* __restrict__ pidx) {
  __shared__ float csh[CB_CODES][16];
  __shared__ float ccsh[CB_CODES];
  const int tid = threadIdx.x;
  const int r0 = blockIdx.x * 512 + tid;
  const int r1 = r0 + 256;
  const int c0 = blockIdx.y * CB_CODES;

  {
    int ci = tid >> 1, half = tid & 1;
    const float4* src = reinterpret_cast<const float4*>(cb + (size_t)(c0 + ci) * 16 + half * 8);
    float4 v0 = src[0], v1 = src[1];
    float4* dst = reinterpret_cast<float4*>(&csh[ci][half * 8]);
    dst[0] = v0; dst[1] = v1;
    if (tid < CB_CODES) {
      const float4* p = reinterpret_cast<const float4*>(cb + (size_t)(c0 + tid) * 16);
      float4 a = p[0], b = p[1], d = p[2], e = p[3];
      ccsh[tid] = a.x*a.x + a.y*a.y + a.z*a.z + a.w*a.w
                + b.x*b.x + b.y*b.y + b.z*b.z + b.w*b.w
                + d.x*d.x + d.y*d.y + d.z*d.z + d.w*d.w
                + e.x*e.x + e.y*e.y + e.z*e.z + e.w*e.w;
    }
  }
  const float4* fp0 = reinterpret_cast<const float4*>(fnorm + (size_t)r0 * 16);
  const float4* fp1 = reinterpret_cast<const float4*>(fnorm + (size_t)r1 * 16);
  float4 a0 = fp0[0], a1 = fp0[1], a2 = fp0[2], a3 = fp0[3];
  float4 b0 = fp1[0], b1 = fp1[1], b2 = fp1[2], b3 = fp1[3];
  __syncthreads();

  float bestA = 3.4e38f, bestB = 3.4e38f;
  int idxA = 0, idxB = 0;
  #pragma unroll 4
  for (int ci = 0; ci < CB_CODES; ++ci) {
    const float4* cvp = reinterpret_cast<const float4*>(&csh[ci][0]);
    float4 c0v = cvp[0], c1v = cvp[1], c2v = cvp[2], c3v = cvp[3];
    float ccv = ccsh[ci];
    float dotA = a0.x*c0v.x + a0.y*c0v.y + a0.z*c0v.z + a0.w*c0v.w
               + a1.x*c1v.x + a1.y*c1v.y + a1.z*c1v.z + a1.w*c1v.w
               + a2.x*c2v.x + a2.y*c2v.y + a2.z*c2v.z + a2.w*c2v.w
               + a3.x*c3v.x + a3.y*c3v.y + a3.z*c3v.z + a3.w*c3v.w;
    float dotB = b0.x*c0v.x + b0.y*c0v.y + b0.z*c0v.z + b0.w*c0v.w
               + b1.x*c1v.x + b1.y*c1v.y + b1.z*c1v.z + b1.w*c1v.w
               + b2.x*c2v.x + b2.y*c2v.y + b2.z*c2v.z + b2.w*c2v.w
               + b3.x*c3v.x + b3.y*c3v.y + b3.z*c3v.z + b3.w*c3v.w;
    float dA = fmaf(-2.f, dotA, ccv);
    float dB = fmaf(-2.f, dotB, ccv);
    if (dA < bestA) { bestA = dA; idxA = c0 + ci; }
    if (dB < bestB) { bestB = dB; idxB = c0 + ci; }
  }
  pval[(size_t)blockIdx.y * MROWS + r0] = bestA;
  pidx[(size_t)blockIdx.y * MROWS + r0] = idxA;
  pval[(size_t)blockIdx.y * MROWS + r1] = bestB;
  pidx[(size_t)blockIdx.y * MROWS + r1] = idxB;
}

// merge partials; also zero rowsum (same index space)
__global__ void merge_targets_kernel(const float* __restrict__ pval, const int* __restrict__ pidx,
                                     int* __restrict__ targets, float* __restrict__ rowsum) {
  int row = blockIdx.x * 256 + threadIdx.x;
  float best = pval[row]; int bi = pidx[row];
  #pragma unroll 8
  for (int b = 1; b < 64; ++b) {
    float v = pval[(size_t)b * MROWS + row];
    int   i = pidx[(size_t)b * MROWS + row];
    if (v < best) { best = v; bi = i; }
  }
  targets[row] = bi;
  rowsum[row] = 0.f;
}

// ---------------- target logit: tgtlog[r] = Abf[r].Bbf[tg] + bias[tg] ----------------
__global__ void tgt_logit_kernel(const unsigned short* __restrict__ A,
                                 const unsigned short* __restrict__ B,
                                 const float* __restrict__ bias,
                                 const int* __restrict__ targets,
                                 float* __restrict__ tgtlog) {
  const int wv = threadIdx.x >> 6, lane = threadIdx.x & 63;
  const int r = blockIdx.x * 4 + wv;
  const int tg = targets[r];
  uint4 ua = reinterpret_cast<const uint4*>(A + (size_t)r * KDIM)[lane];
  uint4 ub = reinterpret_cast<const uint4*>(B + (size_t)tg * KDIM)[lane];
  float s = 0.f;
  const unsigned int* pa = reinterpret_cast<const unsigned int*>(&ua);
  const unsigned int* pb = reinterpret_cast<const unsigned int*>(&ub);
  #pragma unroll
  for (int i = 0; i < 4; ++i) {
    unsigned int a = pa[i], b = pb[i];
    float alo = __uint_as_float(a << 16),  blo = __uint_as_float(b << 16);
    float ahi = __uint_as_float(a & 0xffff0000u), bhi = __uint_as_float(b & 0xffff0000u);
    s += alo * blo + ahi * bhi;
  }
  #pragma unroll
  for (int o = 1; o < 64; o <<= 1) s += __shfl_xor(s, o);
  if (lane == 0) tgtlog[r] = s + bias[tg];
}

// ---------------- GEMM (bf16 MFMA) + fused rowsum(exp) ----------------
#define BM 128
#define BN 128
#define BK 64

__global__ __launch_bounds__(256, 5)
void gemm_ce_kernel(const unsigned short* __restrict__ A,  // [MROWS][KDIM] bf16
                    const unsigned short* __restrict__ B,  // [NCOL][KDIM] bf16 (W^T)
                    const float* __restrict__ bias,
                    float* __restrict__ rowsum) {
  __shared__ unsigned short As[BM][BK];
  __shared__ unsigned short Bs[BN][BK];
  const int tid = threadIdx.x;
  const int wave = tid >> 6;
  const int lane = tid & 63;
  // XCD-aware swizzle: each XCD owns 8 bx columns, by-major within.
  const int bid = blockIdx.x;
  const int xcd = bid & 7, idx = bid >> 3;      // idx in [0,512)
  const int bx = xcd * 8 + (idx & 7);
  const int by = idx >> 3;                      // [0,64)
  const int row0 = by * BM;
  const int col0 = bx * BN;
  const int wr = wave >> 1, wc = wave & 1;

  f32x4 acc[4][4];
  #pragma unroll
  for (int i = 0; i < 4; ++i)
    #pragma unroll
    for (int j = 0; j < 4; ++j) acc[i][j] = (f32x4){0.f, 0.f, 0.f, 0.f};

  const int lr = lane >> 3;
  const int lc = (lane & 7) * 8;

  for (int kt = 0; kt < KDIM; kt += BK) {
    #pragma unroll
    for (int is = 0; is < 4; ++is) {
      int ra = wave * 32 + is * 8 + lr;
      __builtin_amdgcn_global_load_lds(
          (const __attribute__((address_space(1))) void*)(A + (size_t)(row0 + ra) * KDIM + kt + lc),
          (__attribute__((address_space(3))) void*)(&As[wave * 32 + is * 8][0]),
          16, 0, 0);
      __builtin_amdgcn_global_load_lds(
          (const __attribute__((address_space(1))) void*)(B + (size_t)(col0 + ra) * KDIM + kt + lc),
          (__attribute__((address_space(3))) void*)(&Bs[wave * 32 + is * 8][0]),
          16, 0, 0);
    }
    __syncthreads();
    #pragma unroll
    for (int ks = 0; ks < 2; ++ks) {
      const int ke = ks * 32 + (lane >> 4) * 8;
      bf16x8 af[4], bb[4];
      #pragma unroll
      for (int mi = 0; mi < 4; ++mi)
        af[mi] = *(const bf16x8*)&As[wr * 64 + mi * 16 + (lane & 15)][ke];
      #pragma unroll
      for (int ni = 0; ni < 4; ++ni)
        bb[ni] = *(const bf16x8*)&Bs[wc * 64 + ni * 16 + (lane & 15)][ke];
      #pragma unroll
      for (int mi = 0; mi < 4; ++mi)
        #pragma unroll
        for (int ni = 0; ni < 4; ++ni)
          acc[mi][ni] = __builtin_amdgcn_mfma_f32_16x16x32_bf16(af[mi], bb[ni], acc[mi][ni], 0, 0, 0);
    }
    __syncthreads();
  }

  // fused CE epilogue: per-row partial sum(exp(logit))
  float bv[4];
  #pragma unroll
  for (int ni = 0; ni < 4; ++ni)
    bv[ni] = bias[col0 + wc * 64 + ni * 16 + (lane & 15)];
  #pragma unroll
  for (int mi = 0; mi < 4; ++mi) {
    int rbase = row0 + wr * 64 + mi * 16 + (lane >> 4) * 4;
    #pragma unroll
    for (int j = 0; j < 4; ++j) {
      float se = 0.f;
      #pragma unroll
      for (int ni = 0; ni < 4; ++ni)
        se += __expf(acc[mi][ni][j] + bv[ni]);
      #pragma unroll
      for (int o = 1; o < 16; o <<= 1) se += __shfl_xor(se, o);
      if ((lane & 15) == 0) atomicAdd(&rowsum[rbase + j], se);
    }
  }
}

// ---------------- final masked-mean loss ----------------
__global__ void loss_kernel(const float* __restrict__ rowsum, const float* __restrict__ tgtl,
                            const int* __restrict__ lens, float* __restrict__ out) {
  __shared__ float sh[256];
  __shared__ int shc[256];
  int tid = threadIdx.x;
  float s = 0.f; int c = 0;
  for (int r = tid; r < MROWS; r += 256) {
    int n = r >> 11;
    int t = r & (TSEQ - 1);
    if (t < lens[n]) { s += logf(rowsum[r]) - tgtl[r]; c++; }
  }
  sh[tid] = s; shc[tid] = c;
  __syncthreads();
  for (int o = 128; o > 0; o >>= 1) {
    if (tid < o) { sh[tid] += sh[tid + o]; shc[tid] += shc[tid + o]; }
    __syncthreads();
  }
  if (tid == 0) out[0] = sh[0] / (float)max(shc[0], 1);
}

extern "C" void kernel_launch(void* const* d_in, const int* in_sizes, int n_in,
                              void* d_out, int out_size, void* d_ws, size_t ws_size,
                              hipStream_t stream) {
  const float* feats    = (const float*)d_in[0];
  const float* context  = (const float*)d_in[1];
  const int*   lens     = (const int*)d_in[2];
  const float* proj     = (const float*)d_in[3];
  const float* codebook = (const float*)d_in[4];
  const float* W_enc    = (const float*)d_in[5];
  const float* b_enc    = (const float*)d_in[6];
  float* out = (float*)d_out;

  char* ws = (char*)d_ws;
  float* pval    = (float*)(ws);                               // 2 MB (aliases Abf)
  int*   pidx    = (int*)  (ws + 2097152);                     // 2 MB
  unsigned short* Abf = (unsigned short*)(ws);                 // 8 MB
  unsigned short* Bbf = (unsigned short*)(ws + 8388608);       // 8 MB
  float* fnorm   = (float*)(ws + 16777216);                    // 512 KB
  float* rowsum  = (float*)(ws + 17334272);                    // 32 KB
  float* tgtlog  = (float*)(ws + 17367040);                    // 32 KB
  int*   targets = (int*)  (ws + 17399808);                    // 32 KB

  // --- targets first (pval/pidx alias the Abf region) ---
  fproj_kernel<<<MROWS / 16, 256, 0, stream>>>(feats, proj, fnorm);
  {
    dim3 g(MROWS / 512, NCOL / CB_CODES);   // (16, 64)
    targets_part_kernel<<<g, 256, 0, stream>>>(fnorm, codebook, pval, pidx);
  }
  merge_targets_kernel<<<MROWS / 256, 256, 0, stream>>>(pval, pidx, targets, rowsum);

  // --- conversions (safe to overwrite pval/pidx now) ---
  convA_kernel<<<MROWS * KDIM / 4 / 256, 256, 0, stream>>>(context, Abf);
  {
    dim3 g(NCOL / 32, KDIM / 32), b(32, 8);
    convB_kernel<<<g, b, 0, stream>>>(W_enc, Bbf);
  }

  // --- target logit (needs targets + Abf + Bbf) ---
  tgt_logit_kernel<<<MROWS / 4, 256, 0, stream>>>(Abf, Bbf, b_enc, targets, tgtlog);

  // --- fused GEMM + rowsum(exp) ---
  gemm_ce_kernel<<<4096, 256, 0, stream>>>(Abf, Bbf, b_enc, rowsum);
  loss_kernel<<<1, 256, 0, stream>>>(rowsum, tgtlog, lens, out);
}

// Round 5
// 276.619 us; speedup vs baseline: 1.6196x; 1.6196x over previous
//
#include <hip/hip_runtime.h>
#include <hip/hip_bf16.h>

#define MROWS 8192   // N*T
#define KDIM  512    // CIN
#define NCOL  8192   // codebook size K
#define TSEQ  2048

typedef float f32x4 __attribute__((ext_vector_type(4)));
typedef __bf16 bf16x8 __attribute__((ext_vector_type(8)));

__device__ __forceinline__ unsigned short f2bf(float x) {
  unsigned int u = __float_as_uint(x);
  u += 0x7fffu + ((u >> 16) & 1u);
  return (unsigned short)(u >> 16);
}

// ---------------- fused conversions: A cast + B transpose-cast ----------------
// blocks [0,4096): convert context -> Abf (float4 per thread)
// blocks [4096,8192): transpose W_enc [512][8192] -> Bbf [8192][512]
__global__ void convAB_kernel(const float* __restrict__ X, unsigned short* __restrict__ Y,
                              const float* __restrict__ W, unsigned short* __restrict__ Bt) {
  __shared__ float tile[32][33];
  const int tid = threadIdx.x;
  int b = blockIdx.x;
  if (b < 4096) {
    int i = b * 256 + tid;
    float4 v = reinterpret_cast<const float4*>(X)[i];
    ushort4 o;
    o.x = f2bf(v.x); o.y = f2bf(v.y); o.z = f2bf(v.z); o.w = f2bf(v.w);
    reinterpret_cast<ushort4*>(Y)[i] = o;
  } else {
    b -= 4096;
    const int bx = b & 255, by = b >> 8;   // 256 x 16
    const int tx = tid & 31, ty = tid >> 5; // 32 x 8
    #pragma unroll
    for (int i = 0; i < 32; i += 8)
      tile[ty + i][tx] = W[(size_t)(by * 32 + ty + i) * NCOL + bx * 32 + tx];
    __syncthreads();
    #pragma unroll
    for (int i = 0; i < 32; i += 8)
      Bt[(size_t)(bx * 32 + ty + i) * KDIM + by * 32 + tx] = f2bf(tile[tx][ty + i]);
  }
}

// ---------------- f = normalize(feats @ proj), float4 feats loads ----------------
__global__ void fproj_kernel(const float* __restrict__ feats, const float* __restrict__ proj,
                             float* __restrict__ fnorm) {
  int tid = threadIdx.x;            // 256 = 16 rows x 16 dims
  int rl = tid >> 4, d = tid & 15;
  int row = blockIdx.x * 16 + rl;
  const float4* fr4 = reinterpret_cast<const float4*>(feats + (size_t)row * KDIM);
  float acc = 0.f;
  #pragma unroll 4
  for (int kc = 0; kc < KDIM / 4; ++kc) {
    float4 v = fr4[kc];
    const float* p = proj + (size_t)kc * 64 + d;
    acc += v.x * p[0] + v.y * p[16] + v.z * p[32] + v.w * p[48];
  }
  float s = acc * acc;
  #pragma unroll
  for (int o = 1; o < 16; o <<= 1) s += __shfl_xor(s, o);
  float nrm = sqrtf(s);
  fnorm[(size_t)row * 16 + d] = acc / fmaxf(nrm, 1e-12f);
}

// ---------------- nearest codebook (partials, cc fused) ----------------
#define CB_CODES 128
__global__ __launch_bounds__(256)
void targets_part_kernel(const float* __restrict__ fnorm, const float* __restrict__ cb,
                         float* __restrict__ pval, int* __restrict__ pidx) {
  __shared__ float csh[CB_CODES][16];
  __shared__ float ccsh[CB_CODES];
  const int tid = threadIdx.x;
  const int r0 = blockIdx.x * 512 + tid;
  const int r1 = r0 + 256;
  const int c0 = blockIdx.y * CB_CODES;

  {
    int ci = tid >> 1, half = tid & 1;
    const float4* src = reinterpret_cast<const float4*>(cb + (size_t)(c0 + ci) * 16 + half * 8);
    float4 v0 = src[0], v1 = src[1];
    float4* dst = reinterpret_cast<float4*>(&csh[ci][half * 8]);
    dst[0] = v0; dst[1] = v1;
    if (tid < CB_CODES) {
      const float4* p = reinterpret_cast<const float4*>(cb + (size_t)(c0 + tid) * 16);
      float4 a = p[0], b = p[1], d = p[2], e = p[3];
      ccsh[tid] = a.x*a.x + a.y*a.y + a.z*a.z + a.w*a.w
                + b.x*b.x + b.y*b.y + b.z*b.z + b.w*b.w
                + d.x*d.x + d.y*d.y + d.z*d.z + d.w*d.w
                + e.x*e.x + e.y*e.y + e.z*e.z + e.w*e.w;
    }
  }
  const float4* fp0 = reinterpret_cast<const float4*>(fnorm + (size_t)r0 * 16);
  const float4* fp1 = reinterpret_cast<const float4*>(fnorm + (size_t)r1 * 16);
  float4 a0 = fp0[0], a1 = fp0[1], a2 = fp0[2], a3 = fp0[3];
  float4 b0 = fp1[0], b1 = fp1[1], b2 = fp1[2], b3 = fp1[3];
  __syncthreads();

  float bestA = 3.4e38f, bestB = 3.4e38f;
  int idxA = 0, idxB = 0;
  #pragma unroll 4
  for (int ci = 0; ci < CB_CODES; ++ci) {
    const float4* cvp = reinterpret_cast<const float4*>(&csh[ci][0]);
    float4 c0v = cvp[0], c1v = cvp[1], c2v = cvp[2], c3v = cvp[3];
    float ccv = ccsh[ci];
    float dotA = a0.x*c0v.x + a0.y*c0v.y + a0.z*c0v.z + a0.w*c0v.w
               + a1.x*c1v.x + a1.y*c1v.y + a1.z*c1v.z + a1.w*c1v.w
               + a2.x*c2v.x + a2.y*c2v.y + a2.z*c2v.z + a2.w*c2v.w
               + a3.x*c3v.x + a3.y*c3v.y + a3.z*c3v.z + a3.w*c3v.w;
    float dotB = b0.x*c0v.x + b0.y*c0v.y + b0.z*c0v.z + b0.w*c0v.w
               + b1.x*c1v.x + b1.y*c1v.y + b1.z*c1v.z + b1.w*c1v.w
               + b2.x*c2v.x + b2.y*c2v.y + b2.z*c2v.z + b2.w*c2v.w
               + b3.x*c3v.x + b3.y*c3v.y + b3.z*c3v.z + b3.w*c3v.w;
    float dA = fmaf(-2.f, dotA, ccv);
    float dB = fmaf(-2.f, dotB, ccv);
    if (dA < bestA) { bestA = dA; idxA = c0 + ci; }
    if (dB < bestB) { bestB = dB; idxB = c0 + ci; }
  }
  pval[(size_t)blockIdx.y * MROWS + r0] = bestA;
  pidx[(size_t)blockIdx.y * MROWS + r0] = idxA;
  pval[(size_t)blockIdx.y * MROWS + r1] = bestB;
  pidx[(size_t)blockIdx.y * MROWS + r1] = idxB;
}

// merge partials; also zero rowsum (same index space)
__global__ void merge_targets_kernel(const float* __restrict__ pval, const int* __restrict__ pidx,
                                     int* __restrict__ targets, float* __restrict__ rowsum) {
  int row = blockIdx.x * 256 + threadIdx.x;
  float best = pval[row]; int bi = pidx[row];
  #pragma unroll 8
  for (int b = 1; b < 64; ++b) {
    float v = pval[(size_t)b * MROWS + row];
    int   i = pidx[(size_t)b * MROWS + row];
    if (v < best) { best = v; bi = i; }
  }
  targets[row] = bi;
  rowsum[row] = 0.f;
}

// ---------------- target logit: tgtlog[r] = Abf[r].Bbf[tg] + bias[tg] ----------------
__global__ void tgt_logit_kernel(const unsigned short* __restrict__ A,
                                 const unsigned short* __restrict__ B,
                                 const float* __restrict__ bias,
                                 const int* __restrict__ targets,
                                 float* __restrict__ tgtlog) {
  const int wv = threadIdx.x >> 6, lane = threadIdx.x & 63;
  const int r = blockIdx.x * 4 + wv;
  const int tg = targets[r];
  uint4 ua = reinterpret_cast<const uint4*>(A + (size_t)r * KDIM)[lane];
  uint4 ub = reinterpret_cast<const uint4*>(B + (size_t)tg * KDIM)[lane];
  float s = 0.f;
  const unsigned int* pa = reinterpret_cast<const unsigned int*>(&ua);
  const unsigned int* pb = reinterpret_cast<const unsigned int*>(&ub);
  #pragma unroll
  for (int i = 0; i < 4; ++i) {
    unsigned int a = pa[i], b = pb[i];
    float alo = __uint_as_float(a << 16),  blo = __uint_as_float(b << 16);
    float ahi = __uint_as_float(a & 0xffff0000u), bhi = __uint_as_float(b & 0xffff0000u);
    s += alo * blo + ahi * bhi;
  }
  #pragma unroll
  for (int o = 1; o < 64; o <<= 1) s += __shfl_xor(s, o);
  if (lane == 0) tgtlog[r] = s + bias[tg];
}

// ---------------- GEMM (bf16 MFMA, 2-phase LDS double-buffer) + rowsum(exp) ----------------
#define BM 128
#define BN 128
#define BK 64

__device__ __forceinline__ void gld16(const void* g, void* l3) {
  __builtin_amdgcn_global_load_lds((const __attribute__((address_space(1))) void*)g,
                                   (__attribute__((address_space(3))) void*)l3, 16, 0, 0);
}

__global__ __launch_bounds__(256, 2)
void gemm_ce_kernel(const unsigned short* __restrict__ A,  // [MROWS][KDIM] bf16
                    const unsigned short* __restrict__ B,  // [NCOL][KDIM] bf16 (W^T)
                    const float* __restrict__ bias,
                    float* __restrict__ rowsum) {
  __shared__ unsigned short As[2][BM][BK];
  __shared__ unsigned short Bs[2][BN][BK];
  const int tid = threadIdx.x;
  const int wave = tid >> 6;
  const int lane = tid & 63;
  // XCD-aware swizzle: each XCD owns 8 bx columns, by-major within.
  const int bid = blockIdx.x;
  const int xcd = bid & 7, idx = bid >> 3;
  const int bx = xcd * 8 + (idx & 7);
  const int by = idx >> 3;
  const int row0 = by * BM;
  const int col0 = bx * BN;
  const int wr = wave >> 1, wc = wave & 1;

  f32x4 acc[4][4];
  #pragma unroll
  for (int i = 0; i < 4; ++i)
    #pragma unroll
    for (int j = 0; j < 4; ++j) acc[i][j] = (f32x4){0.f, 0.f, 0.f, 0.f};

  const int lr = lane >> 3;
  const int lc = (lane & 7) * 8;

  // prologue: stage tile 0 into buf 0
  #pragma unroll
  for (int is = 0; is < 4; ++is) {
    int ra = wave * 32 + is * 8;
    gld16(A + (size_t)(row0 + ra + lr) * KDIM + lc, &As[0][ra][0]);
    gld16(B + (size_t)(col0 + ra + lr) * KDIM + lc, &Bs[0][ra][0]);
  }
  asm volatile("s_waitcnt vmcnt(0)" ::: "memory");
  __builtin_amdgcn_s_barrier();

  #pragma unroll
  for (int t = 0; t < 8; ++t) {
    const int cur = t & 1;
    // issue next-tile prefetch into the other buffer (stays in flight under compute)
    if (t < 7) {
      const int kt = (t + 1) * BK;
      #pragma unroll
      for (int is = 0; is < 4; ++is) {
        int ra = wave * 32 + is * 8;
        gld16(A + (size_t)(row0 + ra + lr) * KDIM + kt + lc, &As[cur ^ 1][ra][0]);
        gld16(B + (size_t)(col0 + ra + lr) * KDIM + kt + lc, &Bs[cur ^ 1][ra][0]);
      }
    }
    // compute current buffer
    #pragma unroll
    for (int ks = 0; ks < 2; ++ks) {
      const int ke = ks * 32 + (lane >> 4) * 8;
      bf16x8 af[4], bb[4];
      #pragma unroll
      for (int mi = 0; mi < 4; ++mi)
        af[mi] = *(const bf16x8*)&As[cur][wr * 64 + mi * 16 + (lane & 15)][ke];
      #pragma unroll
      for (int ni = 0; ni < 4; ++ni)
        bb[ni] = *(const bf16x8*)&Bs[cur][wc * 64 + ni * 16 + (lane & 15)][ke];
      #pragma unroll
      for (int mi = 0; mi < 4; ++mi)
        #pragma unroll
        for (int ni = 0; ni < 4; ++ni)
          acc[mi][ni] = __builtin_amdgcn_mfma_f32_16x16x32_bf16(af[mi], bb[ni], acc[mi][ni], 0, 0, 0);
    }
    if (t < 7) {
      asm volatile("s_waitcnt vmcnt(0)" ::: "memory");
      __builtin_amdgcn_s_barrier();
    }
  }

  // fused CE epilogue: per-row partial sum(exp(logit))
  float bv[4];
  #pragma unroll
  for (int ni = 0; ni < 4; ++ni)
    bv[ni] = bias[col0 + wc * 64 + ni * 16 + (lane & 15)];
  #pragma unroll
  for (int mi = 0; mi < 4; ++mi) {
    int rbase = row0 + wr * 64 + mi * 16 + (lane >> 4) * 4;
    #pragma unroll
    for (int j = 0; j < 4; ++j) {
      float se = 0.f;
      #pragma unroll
      for (int ni = 0; ni < 4; ++ni)
        se += __expf(acc[mi][ni][j] + bv[ni]);
      #pragma unroll
      for (int o = 1; o < 16; o <<= 1) se += __shfl_xor(se, o);
      if ((lane & 15) == 0) atomicAdd(&rowsum[rbase + j], se);
    }
  }
}

// ---------------- final masked-mean loss ----------------
__global__ void loss_kernel(const float* __restrict__ rowsum, const float* __restrict__ tgtl,
                            const int* __restrict__ lens, float* __restrict__ out) {
  __shared__ float sh[256];
  __shared__ int shc[256];
  int tid = threadIdx.x;
  float s = 0.f; int c = 0;
  for (int r = tid; r < MROWS; r += 256) {
    int n = r >> 11;
    int t = r & (TSEQ - 1);
    if (t < lens[n]) { s += logf(rowsum[r]) - tgtl[r]; c++; }
  }
  sh[tid] = s; shc[tid] = c;
  __syncthreads();
  for (int o = 128; o > 0; o >>= 1) {
    if (tid < o) { sh[tid] += sh[tid + o]; shc[tid] += shc[tid + o]; }
    __syncthreads();
  }
  if (tid == 0) out[0] = sh[0] / (float)max(shc[0], 1);
}

extern "C" void kernel_launch(void* const* d_in, const int* in_sizes, int n_in,
                              void* d_out, int out_size, void* d_ws, size_t ws_size,
                              hipStream_t stream) {
  const float* feats    = (const float*)d_in[0];
  const float* context  = (const float*)d_in[1];
  const int*   lens     = (const int*)d_in[2];
  const float* proj     = (const float*)d_in[3];
  const float* codebook = (const float*)d_in[4];
  const float* W_enc    = (const float*)d_in[5];
  const float* b_enc    = (const float*)d_in[6];
  float* out = (float*)d_out;

  char* ws = (char*)d_ws;
  float* pval    = (float*)(ws);                               // 2 MB (aliases Abf)
  int*   pidx    = (int*)  (ws + 2097152);                     // 2 MB
  unsigned short* Abf = (unsigned short*)(ws);                 // 8 MB
  unsigned short* Bbf = (unsigned short*)(ws + 8388608);       // 8 MB
  float* fnorm   = (float*)(ws + 16777216);                    // 512 KB
  float* rowsum  = (float*)(ws + 17334272);                    // 32 KB
  float* tgtlog  = (float*)(ws + 17367040);                    // 32 KB
  int*   targets = (int*)  (ws + 17399808);                    // 32 KB

  // --- targets first (pval/pidx alias the Abf region) ---
  fproj_kernel<<<MROWS / 16, 256, 0, stream>>>(feats, proj, fnorm);
  {
    dim3 g(MROWS / 512, NCOL / CB_CODES);   // (16, 64)
    targets_part_kernel<<<g, 256, 0, stream>>>(fnorm, codebook, pval, pidx);
  }
  merge_targets_kernel<<<MROWS / 256, 256, 0, stream>>>(pval, pidx, targets, rowsum);

  // --- conversions (safe to overwrite pval/pidx now) ---
  convAB_kernel<<<8192, 256, 0, stream>>>(context, Abf, W_enc, Bbf);

  // --- target logit (needs targets + Abf + Bbf) ---
  tgt_logit_kernel<<<MROWS / 4, 256, 0, stream>>>(Abf, Bbf, b_enc, targets, tgtlog);

  // --- fused GEMM + rowsum(exp) ---
  gemm_ce_kernel<<<4096, 256, 0, stream>>>(Abf, Bbf, b_enc, rowsum);
  loss_kernel<<<1, 256, 0, stream>>>(rowsum, tgtlog, lens, out);
}

// Round 6
// 236.841 us; speedup vs baseline: 1.8916x; 1.1680x over previous
//
#include <hip/hip_runtime.h>
#include <hip/hip_bf16.h>

#define MROWS 8192   // N*T
#define KDIM  512    // CIN
#define NCOL  8192   // codebook size K
#define TSEQ  2048

typedef float f32x4 __attribute__((ext_vector_type(4)));
typedef __bf16 bf16x8 __attribute__((ext_vector_type(8)));

__device__ __forceinline__ unsigned short f2bf(float x) {
  unsigned int u = __float_as_uint(x);
  u += 0x7fffu + ((u >> 16) & 1u);
  return (unsigned short)(u >> 16);
}

// ---------------- fused conversions: A cast + B transpose-cast ----------------
__global__ void convAB_kernel(const float* __restrict__ X, unsigned short* __restrict__ Y,
                              const float* __restrict__ W, unsigned short* __restrict__ Bt) {
  __shared__ float tile[32][33];
  const int tid = threadIdx.x;
  int b = blockIdx.x;
  if (b < 4096) {
    int i = b * 256 + tid;
    float4 v = reinterpret_cast<const float4*>(X)[i];
    ushort4 o;
    o.x = f2bf(v.x); o.y = f2bf(v.y); o.z = f2bf(v.z); o.w = f2bf(v.w);
    reinterpret_cast<ushort4*>(Y)[i] = o;
  } else {
    b -= 4096;
    const int bx = b & 255, by = b >> 8;    // 256 x 16
    const int tx = tid & 31, ty = tid >> 5; // 32 x 8
    #pragma unroll
    for (int i = 0; i < 32; i += 8)
      tile[ty + i][tx] = W[(size_t)(by * 32 + ty + i) * NCOL + bx * 32 + tx];
    __syncthreads();
    #pragma unroll
    for (int i = 0; i < 32; i += 8)
      Bt[(size_t)(bx * 32 + ty + i) * KDIM + by * 32 + tx] = f2bf(tile[tx][ty + i]);
  }
}

// ---------------- f = normalize(feats @ proj) ----------------
__global__ void fproj_kernel(const float* __restrict__ feats, const float* __restrict__ proj,
                             float* __restrict__ fnorm) {
  int tid = threadIdx.x;            // 256 = 16 rows x 16 dims
  int rl = tid >> 4, d = tid & 15;
  int row = blockIdx.x * 16 + rl;
  const float4* fr4 = reinterpret_cast<const float4*>(feats + (size_t)row * KDIM);
  float acc = 0.f;
  #pragma unroll 4
  for (int kc = 0; kc < KDIM / 4; ++kc) {
    float4 v = fr4[kc];
    const float* p = proj + (size_t)kc * 64 + d;
    acc += v.x * p[0] + v.y * p[16] + v.z * p[32] + v.w * p[48];
  }
  float s = acc * acc;
  #pragma unroll
  for (int o = 1; o < 16; o <<= 1) s += __shfl_xor(s, o);
  float nrm = sqrtf(s);
  fnorm[(size_t)row * 16 + d] = acc / fmaxf(nrm, 1e-12f);
}

// ---------------- nearest codebook: 4 rows/thread ----------------
#define CB_CODES 128
__global__ __launch_bounds__(256)
void targets_part_kernel(const float* __restrict__ fnorm, const float* __restrict__ cb,
                         float* __restrict__ pval, int* __restrict__ pidx) {
  __shared__ float csh[CB_CODES][16];
  __shared__ float ccsh[CB_CODES];
  const int tid = threadIdx.x;
  const int r0 = blockIdx.x * 1024 + tid;
  const int c0 = blockIdx.y * CB_CODES;

  {
    int ci = tid >> 1, half = tid & 1;
    const float4* src = reinterpret_cast<const float4*>(cb + (size_t)(c0 + ci) * 16 + half * 8);
    float4 v0 = src[0], v1 = src[1];
    float4* dst = reinterpret_cast<float4*>(&csh[ci][half * 8]);
    dst[0] = v0; dst[1] = v1;
    if (tid < CB_CODES) {
      const float4* p = reinterpret_cast<const float4*>(cb + (size_t)(c0 + tid) * 16);
      float4 a = p[0], b = p[1], d = p[2], e = p[3];
      ccsh[tid] = a.x*a.x + a.y*a.y + a.z*a.z + a.w*a.w
                + b.x*b.x + b.y*b.y + b.z*b.z + b.w*b.w
                + d.x*d.x + d.y*d.y + d.z*d.z + d.w*d.w
                + e.x*e.x + e.y*e.y + e.z*e.z + e.w*e.w;
    }
  }
  float4 fa[4][4];
  #pragma unroll
  for (int q = 0; q < 4; ++q) {
    const float4* fp = reinterpret_cast<const float4*>(fnorm + (size_t)(r0 + q * 256) * 16);
    fa[q][0] = fp[0]; fa[q][1] = fp[1]; fa[q][2] = fp[2]; fa[q][3] = fp[3];
  }
  __syncthreads();

  float best[4] = {3.4e38f, 3.4e38f, 3.4e38f, 3.4e38f};
  int bidx[4] = {0, 0, 0, 0};
  #pragma unroll 2
  for (int ci = 0; ci < CB_CODES; ++ci) {
    const float4* cvp = reinterpret_cast<const float4*>(&csh[ci][0]);
    float4 c0v = cvp[0], c1v = cvp[1], c2v = cvp[2], c3v = cvp[3];
    float ccv = ccsh[ci];
    #pragma unroll
    for (int q = 0; q < 4; ++q) {
      float dot = fa[q][0].x*c0v.x + fa[q][0].y*c0v.y + fa[q][0].z*c0v.z + fa[q][0].w*c0v.w
                + fa[q][1].x*c1v.x + fa[q][1].y*c1v.y + fa[q][1].z*c1v.z + fa[q][1].w*c1v.w
                + fa[q][2].x*c2v.x + fa[q][2].y*c2v.y + fa[q][2].z*c2v.z + fa[q][2].w*c2v.w
                + fa[q][3].x*c3v.x + fa[q][3].y*c3v.y + fa[q][3].z*c3v.z + fa[q][3].w*c3v.w;
      float d = fmaf(-2.f, dot, ccv);
      if (d < best[q]) { best[q] = d; bidx[q] = c0 + ci; }
    }
  }
  #pragma unroll
  for (int q = 0; q < 4; ++q) {
    pval[(size_t)blockIdx.y * MROWS + r0 + q * 256] = best[q];
    pidx[(size_t)blockIdx.y * MROWS + r0 + q * 256] = bidx[q];
  }
}

// merge partials; also zero rowsum (same index space)
__global__ void merge_targets_kernel(const float* __restrict__ pval, const int* __restrict__ pidx,
                                     int* __restrict__ targets, float* __restrict__ rowsum) {
  int row = blockIdx.x * 256 + threadIdx.x;
  float best = pval[row]; int bi = pidx[row];
  #pragma unroll 8
  for (int b = 1; b < 64; ++b) {
    float v = pval[(size_t)b * MROWS + row];
    int   i = pidx[(size_t)b * MROWS + row];
    if (v < best) { best = v; bi = i; }
  }
  targets[row] = bi;
  rowsum[row] = 0.f;
}

// ---------------- target logit: tgtlog[r] = Abf[r].Bbf[tg] + bias[tg] ----------------
__global__ void tgt_logit_kernel(const unsigned short* __restrict__ A,
                                 const unsigned short* __restrict__ B,
                                 const float* __restrict__ bias,
                                 const int* __restrict__ targets,
                                 float* __restrict__ tgtlog) {
  const int wv = threadIdx.x >> 6, lane = threadIdx.x & 63;
  const int r = blockIdx.x * 4 + wv;
  const int tg = targets[r];
  uint4 ua = reinterpret_cast<const uint4*>(A + (size_t)r * KDIM)[lane];
  uint4 ub = reinterpret_cast<const uint4*>(B + (size_t)tg * KDIM)[lane];
  float s = 0.f;
  const unsigned int* pa = reinterpret_cast<const unsigned int*>(&ua);
  const unsigned int* pb = reinterpret_cast<const unsigned int*>(&ub);
  #pragma unroll
  for (int i = 0; i < 4; ++i) {
    unsigned int a = pa[i], b = pb[i];
    float alo = __uint_as_float(a << 16),  blo = __uint_as_float(b << 16);
    float ahi = __uint_as_float(a & 0xffff0000u), bhi = __uint_as_float(b & 0xffff0000u);
    s += alo * blo + ahi * bhi;
  }
  #pragma unroll
  for (int o = 1; o < 64; o <<= 1) s += __shfl_xor(s, o);
  if (lane == 0) tgtlog[r] = s + bias[tg];
}

// ---------------- GEMM (bf16 MFMA, R2 core) + rowsum(exp) ----------------
#define BM 128
#define BN 128
#define BK 64

__device__ __forceinline__ void gld16(const void* g, void* l3) {
  __builtin_amdgcn_global_load_lds((const __attribute__((address_space(1))) void*)g,
                                   (__attribute__((address_space(3))) void*)l3, 16, 0, 0);
}

__global__ __launch_bounds__(256, 4)
void gemm_ce_kernel(const unsigned short* __restrict__ A,  // [MROWS][KDIM] bf16
                    const unsigned short* __restrict__ B,  // [NCOL][KDIM] bf16 (W^T)
                    const float* __restrict__ bias,
                    float* __restrict__ rowsum) {
  __shared__ unsigned short As[BM][BK];
  __shared__ unsigned short Bs[BN][BK];
  const int tid = threadIdx.x;
  const int wave = tid >> 6;
  const int lane = tid & 63;
  // XCD-aware swizzle: each XCD owns 8 bx columns, by-major within.
  const int bid = blockIdx.x;
  const int xcd = bid & 7, idx = bid >> 3;
  const int bx = xcd * 8 + (idx & 7);
  const int by = idx >> 3;
  const int row0 = by * BM;
  const int col0 = bx * BN;
  const int wr = wave >> 1, wc = wave & 1;

  f32x4 acc[4][4];
  #pragma unroll
  for (int i = 0; i < 4; ++i)
    #pragma unroll
    for (int j = 0; j < 4; ++j) acc[i][j] = (f32x4){0.f, 0.f, 0.f, 0.f};

  const int lr = lane >> 3;
  const int lc = (lane & 7) * 8;

  for (int kt = 0; kt < KDIM; kt += BK) {
    #pragma unroll
    for (int is = 0; is < 4; ++is) {
      int ra = wave * 32 + is * 8;
      gld16(A + (size_t)(row0 + ra + lr) * KDIM + kt + lc, &As[ra][0]);
      gld16(B + (size_t)(col0 + ra + lr) * KDIM + kt + lc, &Bs[ra][0]);
    }
    __syncthreads();
    #pragma unroll
    for (int ks = 0; ks < 2; ++ks) {
      const int ke = ks * 32 + (lane >> 4) * 8;
      bf16x8 af[4], bb[4];
      #pragma unroll
      for (int mi = 0; mi < 4; ++mi)
        af[mi] = *(const bf16x8*)&As[wr * 64 + mi * 16 + (lane & 15)][ke];
      #pragma unroll
      for (int ni = 0; ni < 4; ++ni)
        bb[ni] = *(const bf16x8*)&Bs[wc * 64 + ni * 16 + (lane & 15)][ke];
      #pragma unroll
      for (int mi = 0; mi < 4; ++mi)
        #pragma unroll
        for (int ni = 0; ni < 4; ++ni)
          acc[mi][ni] = __builtin_amdgcn_mfma_f32_16x16x32_bf16(af[mi], bb[ni], acc[mi][ni], 0, 0, 0);
    }
    __syncthreads();
  }

  // slim epilogue: per-row partial sum(exp(logit))
  float bv[4];
  #pragma unroll
  for (int ni = 0; ni < 4; ++ni)
    bv[ni] = bias[col0 + wc * 64 + ni * 16 + (lane & 15)];
  #pragma unroll
  for (int mi = 0; mi < 4; ++mi) {
    int rbase = row0 + wr * 64 + mi * 16 + (lane >> 4) * 4;
    #pragma unroll
    for (int j = 0; j < 4; ++j) {
      float se = 0.f;
      #pragma unroll
      for (int ni = 0; ni < 4; ++ni)
        se += __expf(acc[mi][ni][j] + bv[ni]);
      #pragma unroll
      for (int o = 1; o < 16; o <<= 1) se += __shfl_xor(se, o);
      if ((lane & 15) == 0) atomicAdd(&rowsum[rbase + j], se);
    }
  }
}

// ---------------- final masked-mean loss ----------------
__global__ void loss_kernel(const float* __restrict__ rowsum, const float* __restrict__ tgtl,
                            const int* __restrict__ lens, float* __restrict__ out) {
  __shared__ float sh[256];
  __shared__ int shc[256];
  int tid = threadIdx.x;
  float s = 0.f; int c = 0;
  for (int r = tid; r < MROWS; r += 256) {
    int n = r >> 11;
    int t = r & (TSEQ - 1);
    if (t < lens[n]) { s += logf(rowsum[r]) - tgtl[r]; c++; }
  }
  sh[tid] = s; shc[tid] = c;
  __syncthreads();
  for (int o = 128; o > 0; o >>= 1) {
    if (tid < o) { sh[tid] += sh[tid + o]; shc[tid] += shc[tid + o]; }
    __syncthreads();
  }
  if (tid == 0) out[0] = sh[0] / (float)max(shc[0], 1);
}

extern "C" void kernel_launch(void* const* d_in, const int* in_sizes, int n_in,
                              void* d_out, int out_size, void* d_ws, size_t ws_size,
                              hipStream_t stream) {
  const float* feats    = (const float*)d_in[0];
  const float* context  = (const float*)d_in[1];
  const int*   lens     = (const int*)d_in[2];
  const float* proj     = (const float*)d_in[3];
  const float* codebook = (const float*)d_in[4];
  const float* W_enc    = (const float*)d_in[5];
  const float* b_enc    = (const float*)d_in[6];
  float* out = (float*)d_out;

  char* ws = (char*)d_ws;
  float* pval    = (float*)(ws);                               // 2 MB (aliases Abf)
  int*   pidx    = (int*)  (ws + 2097152);                     // 2 MB
  unsigned short* Abf = (unsigned short*)(ws);                 // 8 MB
  unsigned short* Bbf = (unsigned short*)(ws + 8388608);       // 8 MB
  float* fnorm   = (float*)(ws + 16777216);                    // 512 KB
  float* rowsum  = (float*)(ws + 17334272);                    // 32 KB
  float* tgtlog  = (float*)(ws + 17367040);                    // 32 KB
  int*   targets = (int*)  (ws + 17399808);                    // 32 KB

  // --- targets first (pval/pidx alias the Abf region) ---
  fproj_kernel<<<MROWS / 16, 256, 0, stream>>>(feats, proj, fnorm);
  {
    dim3 g(MROWS / 1024, NCOL / CB_CODES);   // (8, 64)
    targets_part_kernel<<<g, 256, 0, stream>>>(fnorm, codebook, pval, pidx);
  }
  merge_targets_kernel<<<MROWS / 256, 256, 0, stream>>>(pval, pidx, targets, rowsum);

  // --- conversions (safe to overwrite pval/pidx now) ---
  convAB_kernel<<<8192, 256, 0, stream>>>(context, Abf, W_enc, Bbf);

  // --- target logit (needs targets + Abf + Bbf) ---
  tgt_logit_kernel<<<MROWS / 4, 256, 0, stream>>>(Abf, Bbf, b_enc, targets, tgtlog);

  // --- fused GEMM + rowsum(exp) ---
  gemm_ce_kernel<<<4096, 256, 0, stream>>>(Abf, Bbf, b_enc, rowsum);
  loss_kernel<<<1, 256, 0, stream>>>(rowsum, tgtlog, lens, out);
}